// Round 1
// 670.052 us; speedup vs baseline: 1.0253x; 1.0253x over previous
//
#include <hip/hip_runtime.h>

#define BATCH 64
#define NPTS  4096
#define LIG   64
#define DIM   512
#define OUTF  7
#define TOPK  10
#define PBLK  8   // pool blocks per batch (partition by idx & 7)

using ull = unsigned long long;

__device__ __forceinline__ ull shfl_down_u64(ull v, int off) {
    unsigned int lo = (unsigned int)v, hi = (unsigned int)(v >> 32);
    lo = __shfl_down(lo, off);
    hi = __shfl_down(hi, off);
    return ((ull)hi << 32) | lo;
}

__device__ __forceinline__ ull umin64(ull a, ull b) { return (a < b) ? a : b; }

__device__ __forceinline__ float dot4(float4 a, float4 b) {
    return a.x * b.x + a.y * b.y + a.z * b.z + a.w * b.w;
}

// ---------------------------------------------------------------------------
// Kernel 1: per (b, ligand-atom) find 10 nearest of 4096 points.
// Thread t owns points t*16..t*16+15. Key = (f32bits(d^2)<<32)|n : u64-min
// == top_k stable lowest-index tie-break (exact vs reference).
// v2: single barrier per round (double-buffered red[], every thread computes
// the global min locally) + winner-only rescan (per-thread running min m;
// only the owning thread re-scans its 16 keys after an extraction).
// ---------------------------------------------------------------------------
__global__ __launch_bounds__(256) void k_topk(
    const float* __restrict__ pos,
    const float* __restrict__ lig,
    int* __restrict__ idxbuf) {
    const int l = blockIdx.x;
    const int b = blockIdx.y;
    const int t = threadIdx.x;

    const float* lp = lig + ((size_t)b * LIG + l) * 3;
    const float lx = lp[0], ly = lp[1], lz = lp[2];

    const float4* src = (const float4*)(pos + (size_t)b * NPTS * 3) + t * 12;
    float w[48];
#pragma unroll
    for (int q = 0; q < 12; ++q) {
        float4 v = src[q];
        w[4 * q] = v.x; w[4 * q + 1] = v.y; w[4 * q + 2] = v.z; w[4 * q + 3] = v.w;
    }

    ull key[16];
#pragma unroll
    for (int i = 0; i < 16; ++i) {
        float dx = w[3 * i]     - lx;
        float dy = w[3 * i + 1] - ly;
        float dz = w[3 * i + 2] - lz;
        float d2 = dx * dx + dy * dy + dz * dz;
        key[i] = ((ull)__float_as_uint(d2) << 32) | (unsigned)(t * 16 + i);
    }

    // per-thread running min
    ull m = key[0];
#pragma unroll
    for (int i = 1; i < 16; ++i) m = umin64(m, key[i]);

    __shared__ ull red[2][4];          // double-buffered: 1 barrier per round
    const int wave = t >> 6, lane = t & 63;
    int* ob = idxbuf + ((size_t)b * LIG + l) * TOPK;

    for (int r = 0; r < TOPK; ++r) {
        ull k = m;
#pragma unroll
        for (int off = 32; off > 0; off >>= 1)
            k = umin64(k, shfl_down_u64(k, off));
        if (lane == 0) red[r & 1][wave] = k;
        __syncthreads();
        const ull g = umin64(umin64(red[r & 1][0], red[r & 1][1]),
                             umin64(red[r & 1][2], red[r & 1][3]));
        const unsigned widx = (unsigned)g;
        if (t == 0) ob[r] = (int)widx;
        // only the owning thread rescans (divergent on one wave only)
        if ((widx >> 4) == (unsigned)t) {
#pragma unroll
            for (int i = 0; i < 16; ++i)
                key[i] = (key[i] == g) ? ~0ull : key[i];
            m = key[0];
#pragma unroll
            for (int i = 1; i < 16; ++i) m = umin64(m, key[i]);
        }
    }
}

// ---------------------------------------------------------------------------
// Kernel 2: per (partition p, batch b): dedup the 640 indices via LDS bitmask
// but only append indices with (idx & 7) == p — an order-independent set
// partition, so the union over the 8 blocks is exactly the unique set with
// no double-count. Each block covers the FULL 512-feature row (thread t owns
// features t and t+256, coalesced 1KB segments), sums its ~n/8 rows with 8
// loads in flight, writes a partial vector. Total unique count via popc of
// the full bitmask (p==0 writes nsel). 512 blocks -> full-GPU latency hiding.
// ---------------------------------------------------------------------------
__global__ __launch_bounds__(256) void k_pool(
    const int* __restrict__ idxbuf,
    const float* __restrict__ x,
    float* __restrict__ partial,
    int* __restrict__ nsel) {
    const int p = blockIdx.x;          // partition 0..7
    const int b = blockIdx.y;
    const int t = threadIdx.x;

    __shared__ unsigned mword[NPTS / 32];   // full 4096-bit dedup mask
    __shared__ int list[LIG * TOPK];        // this partition's unique indices
    __shared__ int cnt;
    __shared__ int tot;
    if (t == 0) { cnt = 0; tot = 0; }
    for (int i = t; i < NPTS / 32; i += 256) mword[i] = 0u;
    __syncthreads();

    const int* ib = idxbuf + (size_t)b * LIG * TOPK;
    for (int j = t; j < LIG * TOPK; j += 256) {
        int idx = ib[j];
        unsigned bit = 1u << (idx & 31);
        unsigned old = atomicOr(&mword[idx >> 5], bit);
        if (!(old & bit) && ((idx & 7) == p)) list[atomicAdd(&cnt, 1)] = idx;
    }
    __syncthreads();

    // total unique count (popc over full mask) — deterministic
    int v = (t < NPTS / 32) ? (int)__popc(mword[t]) : 0;
#pragma unroll
    for (int off = 32; off > 0; off >>= 1) v += __shfl_down(v, off);
    if ((t & 63) == 0) atomicAdd(&tot, v);
    __syncthreads();
    if (p == 0 && t == 0) nsel[b] = tot;

    const int cn = cnt;
    const float* xb = x + (size_t)b * NPTS * DIM + t;
    float a0 = 0.f, a1 = 0.f;
    int j = 0;
    for (; j + 3 < cn; j += 4) {
        int n0 = list[j], n1 = list[j + 1], n2 = list[j + 2], n3 = list[j + 3];
        const float* r0 = xb + (size_t)n0 * DIM;
        const float* r1 = xb + (size_t)n1 * DIM;
        const float* r2 = xb + (size_t)n2 * DIM;
        const float* r3 = xb + (size_t)n3 * DIM;
        float v00 = r0[0], v01 = r0[256];
        float v10 = r1[0], v11 = r1[256];
        float v20 = r2[0], v21 = r2[256];
        float v30 = r3[0], v31 = r3[256];
        a0 += v00 + v10 + v20 + v30;
        a1 += v01 + v11 + v21 + v31;
    }
    for (; j < cn; ++j) {
        const float* r0 = xb + (size_t)list[j] * DIM;
        a0 += r0[0]; a1 += r0[256];
    }

    float* pb = partial + ((size_t)b * PBLK + p) * DIM;
    pb[t] = a0;
    pb[t + 256] = a1;
}

// ---------------------------------------------------------------------------
// Kernel 3: fold the 8 partials (L2-resident, 1 MB) into emb on the fly,
// scale by 1/n_sel, then h[b,j] = emb . W1[j,:] + b1[j]. Wave-per-row dots,
// lane covers 8 contiguous d via two float4 of W1 (coalesced 2KB/row).
// ---------------------------------------------------------------------------
__global__ __launch_bounds__(256) void k_fc1(
    const float* __restrict__ partial,
    const int* __restrict__ nsel,
    const float* __restrict__ W1,
    const float* __restrict__ b1,
    float* __restrict__ h) {
    const int jc = blockIdx.x;
    const int b  = blockIdx.y;
    const int t  = threadIdx.x;
    const int wave = t >> 6, lane = t & 63;

    const float4* pp = (const float4*)(partial + (size_t)b * PBLK * DIM) + lane * 2;
    float4 e0 = pp[0], e1 = pp[1];
#pragma unroll
    for (int r = 1; r < PBLK; ++r) {
        float4 u0 = pp[r * (DIM / 4)], u1 = pp[r * (DIM / 4) + 1];
        e0.x += u0.x; e0.y += u0.y; e0.z += u0.z; e0.w += u0.w;
        e1.x += u1.x; e1.y += u1.y; e1.z += u1.z; e1.w += u1.w;
    }
    const float inv = 1.0f / (float)nsel[b];
    e0.x *= inv; e0.y *= inv; e0.z *= inv; e0.w *= inv;
    e1.x *= inv; e1.y *= inv; e1.z *= inv; e1.w *= inv;

#pragma unroll
    for (int q = 0; q < 16; ++q) {
        const int jj = jc * 64 + wave * 16 + q;
        const float4* wp = (const float4*)(W1 + (size_t)jj * DIM) + lane * 2;
        float s = dot4(wp[0], e0) + dot4(wp[1], e1);
#pragma unroll
        for (int off = 32; off > 0; off >>= 1) s += __shfl_down(s, off);
        if (lane == 0) h[(size_t)b * DIM + jj] = s + b1[jj];
    }
}

// ---------------------------------------------------------------------------
// Kernel 4: BatchNorm1d (training stats, biased var over B=64) + SiLU.
// 1 block, 512 threads, thread = feature. Coalesced column reads (L2-hot).
// ---------------------------------------------------------------------------
__global__ __launch_bounds__(512) void k_bn(
    const float* __restrict__ h,
    const float* __restrict__ gamma,
    const float* __restrict__ beta,
    float* __restrict__ hs) {
    const int jf = threadIdx.x;
    float s = 0.f, ss = 0.f;
#pragma unroll 8
    for (int b = 0; b < BATCH; ++b) {
        float v = h[(size_t)b * DIM + jf];
        s += v; ss += v * v;
    }
    const float mu  = s * (1.0f / BATCH);
    const float var = ss * (1.0f / BATCH) - mu * mu;
    const float inv = rsqrtf(var + 1e-5f);
    const float g  = gamma[jf];
    const float be = beta[jf];
#pragma unroll 8
    for (int b = 0; b < BATCH; ++b) {
        float v = h[(size_t)b * DIM + jf];
        float u = g * (v - mu) * inv + be;
        hs[(size_t)b * DIM + jf] = u / (1.0f + __expf(-u));   // u * sigmoid(u)
    }
}

// ---------------------------------------------------------------------------
// Kernel 5: out[b,o] = hs[b,:] . W2[o,:] + b2[o]. One wave per batch row.
// ---------------------------------------------------------------------------
__global__ __launch_bounds__(64) void k_fc2(
    const float* __restrict__ hs,
    const float* __restrict__ W2,
    const float* __restrict__ b2,
    float* __restrict__ out) {
    const int b = blockIdx.x;
    const int lane = threadIdx.x;
    const float4* hp = (const float4*)(hs + (size_t)b * DIM) + lane * 2;
    float4 h0 = hp[0], h1 = hp[1];
#pragma unroll
    for (int o = 0; o < OUTF; ++o) {
        const float4* wp = (const float4*)(W2 + (size_t)o * DIM) + lane * 2;
        float s = dot4(wp[0], h0) + dot4(wp[1], h1);
#pragma unroll
        for (int off = 32; off > 0; off >>= 1) s += __shfl_down(s, off);
        if (lane == 0) out[(size_t)b * OUTF + o] = s + b2[o];
    }
}

extern "C" void kernel_launch(void* const* d_in, const int* in_sizes, int n_in,
                              void* d_out, int out_size, void* d_ws, size_t ws_size,
                              hipStream_t stream) {
    const float* pos   = (const float*)d_in[0];
    const float* x     = (const float*)d_in[1];
    const float* lig   = (const float*)d_in[2];
    const float* W1    = (const float*)d_in[3];
    const float* b1    = (const float*)d_in[4];
    const float* gamma = (const float*)d_in[5];
    const float* beta  = (const float*)d_in[6];
    const float* W2    = (const float*)d_in[7];
    const float* b2    = (const float*)d_in[8];
    float* out = (float*)d_out;

    char* ws = (char*)d_ws;
    int*   idxbuf  = (int*)ws;                                        // 64*64*10*4 = 160 KB
    float* partial = (float*)(ws + (size_t)BATCH * LIG * TOPK * 4);   // B*PBLK*D f32 = 1 MB
    int*   nsel    = (int*)((char*)partial + (size_t)BATCH * PBLK * DIM * 4); // B ints
    float* h       = (float*)((char*)nsel + 256);                     // B*D f32
    float* hs      = h + BATCH * DIM;                                 // B*D f32

    k_topk<<<dim3(LIG, BATCH), 256, 0, stream>>>(pos, lig, idxbuf);
    k_pool<<<dim3(PBLK, BATCH), 256, 0, stream>>>(idxbuf, x, partial, nsel);
    k_fc1 <<<dim3(8, BATCH), 256, 0, stream>>>(partial, nsel, W1, b1, h);
    k_bn  <<<1, 512, 0, stream>>>(h, gamma, beta, hs);
    k_fc2 <<<BATCH, 64, 0, stream>>>(hs, W2, b2, out);
}